// Round 4
// baseline (2147.599 us; speedup 1.0000x reference)
//
#include <hip/hip_runtime.h>

// ---------------------------------------------------------------------------
// helpers: cross-lane primitives (VALU where possible; DS only for xor4)
// ---------------------------------------------------------------------------
__device__ __forceinline__ int   f2i(float x){ return __builtin_bit_cast(int, x); }
__device__ __forceinline__ float i2f(int x)  { return __builtin_bit_cast(float, x); }

template<int CTRL>
__device__ __forceinline__ float dppf(float x){
    return i2f(__builtin_amdgcn_mov_dpp(f2i(x), CTRL, 0xF, 0xF, true));
}
template<int PAT>
__device__ __forceinline__ float swzf(float x){
    return i2f(__builtin_amdgcn_ds_swizzle(f2i(x), PAT));
}
// xor32 via permlane32_swap, convention-immune: self-swap returns the two
// 32-half duplicates in some order; partner = r0 + r1 - own.
__device__ __forceinline__ float xor32f(float x){
    unsigned ux = __builtin_bit_cast(unsigned, x);
    auto r = __builtin_amdgcn_permlane32_swap(ux, ux, false, false);
    float a = __builtin_bit_cast(float, (unsigned)r[0]);
    float b = __builtin_bit_cast(float, (unsigned)r[1]);
    return (a + b) - x;
}
#if defined(__has_builtin)
#if __has_builtin(__builtin_amdgcn_permlane16_swap)
#define HAVE_PL16 1
#endif
#endif
__device__ __forceinline__ float xor16f(float x){
#ifdef HAVE_PL16
    unsigned ux = __builtin_bit_cast(unsigned, x);
    auto r = __builtin_amdgcn_permlane16_swap(ux, ux, false, false);
    float a = __builtin_bit_cast(float, (unsigned)r[0]);
    float b = __builtin_bit_cast(float, (unsigned)r[1]);
    return (a + b) - x;
#else
    return swzf<0x401F>(x);
#endif
}
// lane-xor on bit B
template<int B>
__device__ __forceinline__ float lx(float x){
    if constexpr      (B == 0) return dppf<0xB1>(x);    // quad_perm [1,0,3,2]
    else if constexpr (B == 1) return dppf<0x4E>(x);    // quad_perm [2,3,0,1]
    else if constexpr (B == 2) return swzf<0x101F>(x);  // ds_swizzle xor4 (DS)
    else if constexpr (B == 3) return dppf<0x128>(x);   // row_ror:8 == xor8
    else if constexpr (B == 4) return xor16f(x);        // permlane16_swap
    else                       return xor32f(x);        // permlane32_swap
}

// ---------------------------------------------------------------------------
// prep: build 60 fused gate matrices U = RZ*RY*RX from q_params (f32)
// ---------------------------------------------------------------------------
__global__ void k_prep(const float* __restrict__ qp, float* __restrict__ ws)
{
    int t = threadIdx.x;
    if (t >= 60) return;
    int l = t / 10;
    float tx = 0.5f * qp[t*3 + 0];
    float ty = 0.5f * qp[t*3 + 1];
    float tz = 0.5f * qp[t*3 + 2];
    float cx = cosf(tx), sx = sinf(tx);
    float cy = cosf(ty), sy = sinf(ty);
    float cz, sz;
    if (l == 5) { cz = 1.0f; sz = 0.0f; }   // final RZ commutes with Z readout
    else        { cz = cosf(tz); sz = sinf(tz); }
    float m00r =  cy*cx, m00i =  sy*sx;
    float m01r = -sy*cx, m01i = -cy*sx;
    float m10r =  sy*cx, m10i = -cy*sx;
    float m11r =  cy*cx, m11i = -sy*sx;
    float* U = ws + t*8;
    U[0] = m00r*cz + m00i*sz;  U[1] = m00i*cz - m00r*sz;
    U[2] = m01r*cz + m01i*sz;  U[3] = m01i*cz - m01r*sz;
    U[4] = m10r*cz - m10i*sz;  U[5] = m10i*cz + m10r*sz;
    U[6] = m11r*cz - m11i*sz;  U[7] = m11i*cz + m11r*sz;
}

// ---------------------------------------------------------------------------
// quantum sim: 1 wave = 2 samples; qubit q<6 -> lane bit q, q>=6 -> reg bit
// ---------------------------------------------------------------------------
__device__ __forceinline__ void chain16(float (&ar)[16], float (&ai)[16],
                                        int baddr, bool lpar)
{
    // composed CNOT(0,1)..CNOT(8,9): bit k -> parity(b0..bk)
    #pragma unroll
    for (int k = 0; k < 8; k++) {       // conditional pair swap (lane parity)
        float e0 = ar[2*k], o0 = ar[2*k+1];
        ar[2*k]   = lpar ? o0 : e0;
        ar[2*k+1] = lpar ? e0 : o0;
        float e1 = ai[2*k], o1 = ai[2*k+1];
        ai[2*k]   = lpar ? o1 : e1;
        ai[2*k+1] = lpar ? e1 : o1;
    }
    auto BPf = [&](float v){ return i2f(__builtin_amdgcn_ds_bpermute(baddr, f2i(v))); };
    // reg map f cycles: {0},{8},(1,3,5,15),(2,6,10,14),(4,12),(7,9,11,13)
    ar[0] = BPf(ar[0]);  ai[0] = BPf(ai[0]);
    ar[8] = BPf(ar[8]);  ai[8] = BPf(ai[8]);
    { float t=ar[1]; ar[1]=BPf(ar[3]);  ar[3]=BPf(ar[5]);
      ar[5]=BPf(ar[15]); ar[15]=BPf(t); }
    { float t=ai[1]; ai[1]=BPf(ai[3]);  ai[3]=BPf(ai[5]);
      ai[5]=BPf(ai[15]); ai[15]=BPf(t); }
    { float t=ar[2]; ar[2]=BPf(ar[6]);  ar[6]=BPf(ar[10]);
      ar[10]=BPf(ar[14]); ar[14]=BPf(t); }
    { float t=ai[2]; ai[2]=BPf(ai[6]);  ai[6]=BPf(ai[10]);
      ai[10]=BPf(ai[14]); ai[14]=BPf(t); }
    { float t=ar[4]; ar[4]=BPf(ar[12]); ar[12]=BPf(t); }
    { float t=ai[4]; ai[4]=BPf(ai[12]); ai[12]=BPf(t); }
    { float t=ar[7]; ar[7]=BPf(ar[9]);  ar[9]=BPf(ar[11]);
      ar[11]=BPf(ar[13]); ar[13]=BPf(t); }
    { float t=ai[7]; ai[7]=BPf(ai[9]);  ai[9]=BPf(ai[11]);
      ai[11]=BPf(ai[13]); ai[13]=BPf(t); }
}

template<int Q>
__device__ __forceinline__ void lane_gate2(float (&arA)[16], float (&aiA)[16],
                                           float (&arB)[16], float (&aiB)[16],
                                           const float* __restrict__ U, int lane)
{
    float u00r=U[0], u00i=U[1], u01r=U[2], u01i=U[3];
    float u10r=U[4], u10i=U[5], u11r=U[6], u11i=U[7];
    bool hi = (lane >> Q) & 1;
    float msr = hi ? u11r : u00r, msi = hi ? u11i : u00i;
    float mor = hi ? u10r : u01r, moi = hi ? u10i : u01i;
    #pragma unroll
    for (int r = 0; r < 16; r++){
        float oAr = lx<Q>(arA[r]);
        float oAi = lx<Q>(aiA[r]);
        float oBr = lx<Q>(arB[r]);
        float oBi = lx<Q>(aiB[r]);
        float nAr = msr*arA[r] - msi*aiA[r] + mor*oAr - moi*oAi;
        float nAi = msr*aiA[r] + msi*arA[r] + mor*oAi + moi*oAr;
        float nBr = msr*arB[r] - msi*aiB[r] + mor*oBr - moi*oBi;
        float nBi = msr*aiB[r] + msi*arB[r] + mor*oBi + moi*oBr;
        arA[r] = nAr; aiA[r] = nAi;
        arB[r] = nBr; aiB[r] = nBi;
    }
}

// init one sample's state from its encoding angles (+layer-0 gates folded)
__device__ __forceinline__ void init_state(float (&ar)[16], float (&ai)[16],
                                           const float (&cv)[10], const float (&sv)[10],
                                           const float* __restrict__ U0, int lane)
{
    float Lr, Li;
    {
        float v0r = U0[0]*cv[0] + U0[2]*sv[0], v0i = U0[1]*cv[0] + U0[3]*sv[0];
        float v1r = U0[4]*cv[0] + U0[6]*sv[0], v1i = U0[5]*cv[0] + U0[7]*sv[0];
        bool b = lane & 1;
        Lr = b ? v1r : v0r;  Li = b ? v1i : v0i;
    }
    #pragma unroll
    for (int q = 1; q < 6; q++) {
        const float* U = U0 + q*8;
        float v0r = U[0]*cv[q] + U[2]*sv[q], v0i = U[1]*cv[q] + U[3]*sv[q];
        float v1r = U[4]*cv[q] + U[6]*sv[q], v1i = U[5]*cv[q] + U[7]*sv[q];
        bool b = (lane >> q) & 1;
        float fr = b ? v1r : v0r, fi = b ? v1i : v0i;
        float nr = Lr*fr - Li*fi;
        float ni = Lr*fi + Li*fr;
        Lr = nr; Li = ni;
    }
    float vr[4][2], vi[4][2];
    #pragma unroll
    for (int q = 6; q < 10; q++) {
        const float* U = U0 + q*8;
        vr[q-6][0] = U[0]*cv[q] + U[2]*sv[q];  vi[q-6][0] = U[1]*cv[q] + U[3]*sv[q];
        vr[q-6][1] = U[4]*cv[q] + U[6]*sv[q];  vi[q-6][1] = U[5]*cv[q] + U[7]*sv[q];
    }
    float t67r[4], t67i[4], t89r[4], t89i[4];
    #pragma unroll
    for (int m = 0; m < 4; m++) {
        int b0 = m & 1, b1i = (m >> 1) & 1;
        t67r[m] = vr[0][b0]*vr[1][b1i] - vi[0][b0]*vi[1][b1i];
        t67i[m] = vr[0][b0]*vi[1][b1i] + vi[0][b0]*vr[1][b1i];
        t89r[m] = vr[2][b0]*vr[3][b1i] - vi[2][b0]*vi[3][b1i];
        t89i[m] = vr[2][b0]*vi[3][b1i] + vi[2][b0]*vr[3][b1i];
    }
    #pragma unroll
    for (int r = 0; r < 16; r++) {
        int lo = r & 3, hi = r >> 2;
        float pr  = t67r[lo]*t89r[hi] - t67i[lo]*t89i[hi];
        float pi_ = t67r[lo]*t89i[hi] + t67i[lo]*t89r[hi];
        ar[r] = Lr*pr - Li*pi_;
        ai[r] = Lr*pi_ + Li*pr;
    }
}

template<int B>
__device__ __forceinline__ float bf_signed(float v, int lane){
    float t = lx<B>(v);
    return ((lane >> B) & 1) ? (t - v) : (v - t);
}
template<int B>
__device__ __forceinline__ float bf_plain(float v){ return v + lx<B>(v); }

template<int I>
__device__ __forceinline__ float z_mixed(float S, int lane){
    float v = bf_signed<0>(S, lane);
    if constexpr (I >= 1) v = bf_signed<1>(v, lane); else v = bf_plain<1>(v);
    if constexpr (I >= 2) v = bf_signed<2>(v, lane); else v = bf_plain<2>(v);
    if constexpr (I >= 3) v = bf_signed<3>(v, lane); else v = bf_plain<3>(v);
    if constexpr (I >= 4) v = bf_signed<4>(v, lane); else v = bf_plain<4>(v);
    if constexpr (I >= 5) v = bf_signed<5>(v, lane); else v = bf_plain<5>(v);
    return v;
}

__device__ __forceinline__ void readout10(const float (&ar)[16], const float (&ai)[16],
                                          int lane, float (&z)[10])
{
    float p[16];
    #pragma unroll
    for (int r = 0; r < 16; r++) p[r] = ar[r]*ar[r] + ai[r]*ai[r];
    float us[8], ds[8];
    #pragma unroll
    for (int k = 0; k < 8; k++) { us[k] = p[2*k] + p[2*k+1]; ds[k] = p[2*k] - p[2*k+1]; }
    float S  = ((us[0]+us[1]) + (us[2]+us[3])) + ((us[4]+us[5]) + (us[6]+us[7]));
    float T0 = ((ds[0]+ds[1]) + (ds[2]+ds[3])) + ((ds[4]+ds[5]) + (ds[6]+ds[7]));
    float e0 = ds[0]-ds[1], e1 = ds[2]-ds[3], e2 = ds[4]-ds[5], e3 = ds[6]-ds[7];
    float T1 = (e0+e1) + (e2+e3);
    float f0 = e0-e1, f1 = e2-e3;
    float T2 = f0 + f1;
    float T3 = f0 - f1;
    z[0] = z_mixed<0>(S, lane);
    z[1] = z_mixed<1>(S, lane);
    z[2] = z_mixed<2>(S, lane);
    z[3] = z_mixed<3>(S, lane);
    z[4] = z_mixed<4>(S, lane);
    z[5] = z_mixed<5>(S, lane);
    z[6] = z_mixed<5>(T0, lane);
    z[7] = z_mixed<5>(T1, lane);
    z[8] = z_mixed<5>(T2, lane);
    z[9] = z_mixed<5>(T3, lane);
}

__global__ __launch_bounds__(256, 3) void k_qsim(
        const float* __restrict__ x,
        const float* __restrict__ W1, const float* __restrict__ b1,
        const float* __restrict__ W2, const float* __restrict__ b2,
        const float* __restrict__ ws,
        const float* __restrict__ W3, const float* __restrict__ b3,
        const float* __restrict__ W4, const float* __restrict__ b4,
        float* __restrict__ out)
{
    const int lane = threadIdx.x & 63;
    int wid0 = (blockIdx.x * 256 + threadIdx.x) >> 6;
    const int wid = __builtin_amdgcn_readfirstlane(wid0);   // wave id = sample pair

    // ---- fused front MLP for BOTH samples (half-wave each) -----------------
    // lanes 0-31: sample A rows; lanes 32-63: sample B rows.
    float cvA[10], svA[10], cvB[10], svB[10];
    {
        const int j   = lane & 31;
        const int sel = lane >> 5;
        const float* xr  = x + (2*wid + sel) * 64;   // uniform per half-wave
        const float* w1r = W1 + j * 64;
        float a = b1[j];
        #pragma unroll
        for (int k = 0; k < 64; k += 4) {
            float4 xv = *reinterpret_cast<const float4*>(xr + k);
            float4 wv = *reinterpret_cast<const float4*>(w1r + k);
            a = fmaf(wv.x, xv.x, a);
            a = fmaf(wv.y, xv.y, a);
            a = fmaf(wv.z, xv.z, a);
            a = fmaf(wv.w, xv.w, a);
        }
        float h = fmaxf(a, 0.0f);

        float tsel = 0.0f;
        #pragma unroll
        for (int i = 0; i < 10; i++) {
            float t = W2[i*32 + j] * h;
            // sum within each 32-lane half (bits 4..0)
            t = bf_plain<4>(t);  t = bf_plain<3>(t);  t = bf_plain<2>(t);
            t = bf_plain<1>(t);  t = bf_plain<0>(t);
            t += b2[i];
            if (j == i) tsel = t;         // lane i (A) / lane 32+i (B)
        }
        float ang = tanhf(tsel) * 1.5707963267948966f;   // (tanh*pi)*0.5
        float sA, cA;
        __sincosf(ang, &sA, &cA);
        #pragma unroll
        for (int q = 0; q < 10; q++) {
            cvA[q] = i2f(__builtin_amdgcn_readlane(f2i(cA), q));
            svA[q] = i2f(__builtin_amdgcn_readlane(f2i(sA), q));
            cvB[q] = i2f(__builtin_amdgcn_readlane(f2i(cA), 32 + q));
            svB[q] = i2f(__builtin_amdgcn_readlane(f2i(sA), 32 + q));
        }
    }

    float arA[16], aiA[16], arB[16], aiB[16];
    init_state(arA, aiA, cvA, svA, ws, lane);
    init_state(arB, aiB, cvB, svB, ws, lane);

    const int  baddr = ((lane ^ (lane << 1)) & 63) << 2;
    const bool lpar  = __builtin_popcount(lane & 63) & 1;

    // ---- layers: chain(l-1) then gates(l), l = 1..5 (last chain folded) ----
    #pragma unroll 1
    for (int l = 1; l < 6; ++l) {
        chain16(arA, aiA, baddr, lpar);
        chain16(arB, aiB, baddr, lpar);
        const float* Ub = ws + l * 80;
        lane_gate2<0>(arA, aiA, arB, aiB, Ub +  0, lane);
        lane_gate2<1>(arA, aiA, arB, aiB, Ub +  8, lane);
        lane_gate2<2>(arA, aiA, arB, aiB, Ub + 16, lane);
        lane_gate2<3>(arA, aiA, arB, aiB, Ub + 24, lane);
        lane_gate2<4>(arA, aiA, arB, aiB, Ub + 32, lane);
        lane_gate2<5>(arA, aiA, arB, aiB, Ub + 40, lane);
        // register-bit qubits 6..9 (both samples in one loop for ILP)
        #pragma unroll
        for (int qq = 0; qq < 4; qq++) {
            const float* U = Ub + (6+qq)*8;
            float u00r=U[0], u00i=U[1], u01r=U[2], u01i=U[3];
            float u10r=U[4], u10i=U[5], u11r=U[6], u11i=U[7];
            const int m = 1 << qq;
            #pragma unroll
            for (int r = 0; r < 16; r++) {
                if (!(r & m)) {
                    const int r2 = r | m;
                    float a0r=arA[r], a0i=aiA[r], a1r=arA[r2], a1i=aiA[r2];
                    arA[r]  = u00r*a0r - u00i*a0i + u01r*a1r - u01i*a1i;
                    aiA[r]  = u00r*a0i + u00i*a0r + u01r*a1i + u01i*a1r;
                    arA[r2] = u10r*a0r - u10i*a0i + u11r*a1r - u11i*a1i;
                    aiA[r2] = u10r*a0i + u10i*a0r + u11r*a1i + u11i*a1r;
                    float b0r=arB[r], b0i=aiB[r], b1r=arB[r2], b1i=aiB[r2];
                    arB[r]  = u00r*b0r - u00i*b0i + u01r*b1r - u01i*b1i;
                    aiB[r]  = u00r*b0i + u00i*b0r + u01r*b1i + u01i*b1r;
                    arB[r2] = u10r*b0r - u10i*b0i + u11r*b1r - u11i*b1i;
                    aiB[r2] = u10r*b0i + u10i*b0r + u11r*b1i + u11i*b1r;
                }
            }
        }
    }

    // ---- readout + tail MLP for both samples -------------------------------
    float zA[10], zB[10];
    readout10(arA, aiA, lane, zA);
    readout10(arB, aiB, lane, zB);

    float a0A = b4[0], a1A = b4[1], a0B = b4[0], a1B = b4[1];
    #pragma unroll
    for (int j2 = 0; j2 < 16; j2++) {
        float aA = b3[j2], aB = b3[j2];
        #pragma unroll
        for (int q = 0; q < 10; q++) {
            float w = W3[j2*10 + q];
            aA = fmaf(w, zA[q], aA);
            aB = fmaf(w, zB[q], aB);
        }
        aA = fmaxf(aA, 0.0f);
        aB = fmaxf(aB, 0.0f);
        float w40 = W4[j2], w41 = W4[16 + j2];
        a0A = fmaf(w40, aA, a0A);
        a1A = fmaf(w41, aA, a1A);
        a0B = fmaf(w40, aB, a0B);
        a1B = fmaf(w41, aB, a1B);
    }
    if (lane == 0) {
        float4 o; o.x = a0A; o.y = a1A; o.z = a0B; o.w = a1B;
        reinterpret_cast<float4*>(out)[wid] = o;
    }
}

extern "C" void kernel_launch(void* const* d_in, const int* in_sizes, int n_in,
                              void* d_out, int out_size, void* d_ws, size_t ws_size,
                              hipStream_t stream)
{
    (void)in_sizes; (void)n_in; (void)out_size; (void)ws_size;
    const float* x  = (const float*)d_in[0];
    const float* W1 = (const float*)d_in[1];
    const float* b1 = (const float*)d_in[2];
    const float* W2 = (const float*)d_in[3];
    const float* b2 = (const float*)d_in[4];
    const float* qp = (const float*)d_in[5];
    const float* W3 = (const float*)d_in[6];
    const float* b3 = (const float*)d_in[7];
    const float* W4 = (const float*)d_in[8];
    const float* b4 = (const float*)d_in[9];
    float* ws  = (float*)d_ws;
    float* out = (float*)d_out;

    k_prep<<<1, 64, 0, stream>>>(qp, ws);
    k_qsim<<<2048, 256, 0, stream>>>(x, W1, b1, W2, b2, ws, W3, b3, W4, b4, out);
}

// Round 5
// 374.738 us; speedup vs baseline: 5.7309x; 5.7309x over previous
//
#include <hip/hip_runtime.h>

// ---------------------------------------------------------------------------
// helpers: cross-lane primitives (all VALU except ds_bpermute in the chain
// and one xor4 swizzle in the front-MLP reduce)
// ---------------------------------------------------------------------------
__device__ __forceinline__ int   f2i(float x){ return __builtin_bit_cast(int, x); }
__device__ __forceinline__ float i2f(int x)  { return __builtin_bit_cast(float, x); }

template<int CTRL>
__device__ __forceinline__ float dppf(float x){
    return i2f(__builtin_amdgcn_mov_dpp(f2i(x), CTRL, 0xF, 0xF, true));
}
template<int PAT>
__device__ __forceinline__ float swzf(float x){
    return i2f(__builtin_amdgcn_ds_swizzle(f2i(x), PAT));
}
// xor32 via permlane32_swap, convention-immune: self-swap returns the two
// 32-half duplicates in some order; partner = r0 + r1 - own.
__device__ __forceinline__ float xor32f(float x){
    unsigned ux = __builtin_bit_cast(unsigned, x);
    auto r = __builtin_amdgcn_permlane32_swap(ux, ux, false, false);
    float a = __builtin_bit_cast(float, (unsigned)r[0]);
    float b = __builtin_bit_cast(float, (unsigned)r[1]);
    return (a + b) - x;
}
#if defined(__has_builtin)
#if __has_builtin(__builtin_amdgcn_permlane16_swap)
#define HAVE_PL16 1
#endif
#endif
__device__ __forceinline__ float xor16f(float x){
#ifdef HAVE_PL16
    unsigned ux = __builtin_bit_cast(unsigned, x);
    auto r = __builtin_amdgcn_permlane16_swap(ux, ux, false, false);
    float a = __builtin_bit_cast(float, (unsigned)r[0]);
    float b = __builtin_bit_cast(float, (unsigned)r[1]);
    return (a + b) - x;
#else
    return swzf<0x401F>(x);
#endif
}
// lane-xor on bit B
template<int B>
__device__ __forceinline__ float lx(float x){
    if constexpr      (B == 0) return dppf<0xB1>(x);    // quad_perm [1,0,3,2]
    else if constexpr (B == 1) return dppf<0x4E>(x);    // quad_perm [2,3,0,1]
    else if constexpr (B == 2) return swzf<0x101F>(x);  // ds_swizzle xor4 (DS)
    else if constexpr (B == 3) return dppf<0x128>(x);   // row_ror:8 == xor8
    else if constexpr (B == 4) return xor16f(x);        // permlane16_swap
    else                       return xor32f(x);        // permlane32_swap
}

// ---------------------------------------------------------------------------
// prep: build 60 fused gate matrices U = RZ*RY*RX from q_params (f32)
// ---------------------------------------------------------------------------
__global__ void k_prep(const float* __restrict__ qp, float* __restrict__ ws)
{
    int t = threadIdx.x;
    if (t >= 60) return;
    int l = t / 10;
    float tx = 0.5f * qp[t*3 + 0];
    float ty = 0.5f * qp[t*3 + 1];
    float tz = 0.5f * qp[t*3 + 2];
    float cx = cosf(tx), sx = sinf(tx);
    float cy = cosf(ty), sy = sinf(ty);
    float cz, sz;
    if (l == 5) { cz = 1.0f; sz = 0.0f; }   // final RZ commutes with Z readout
    else        { cz = cosf(tz); sz = sinf(tz); }
    float m00r =  cy*cx, m00i =  sy*sx;
    float m01r = -sy*cx, m01i = -cy*sx;
    float m10r =  sy*cx, m10i = -cy*sx;
    float m11r =  cy*cx, m11i = -sy*sx;
    float* U = ws + t*8;
    U[0] = m00r*cz + m00i*sz;  U[1] = m00i*cz - m00r*sz;
    U[2] = m01r*cz + m01i*sz;  U[3] = m01i*cz - m01r*sz;
    U[4] = m10r*cz - m10i*sz;  U[5] = m10i*cz + m10r*sz;
    U[6] = m11r*cz - m11i*sz;  U[7] = m11i*cz + m11r*sz;
}

// ---------------------------------------------------------------------------
// quantum sim: 1 wave = 2 samples.
// qubits 0..4 -> lane bits {0,1,3,4,5}; qubits 5..9 -> reg bits 0..4 (32 regs)
// lane bit 2 = sample index (A: bit2=0, B: bit2=1). No qubit on lane bit 2.
// ---------------------------------------------------------------------------

// composed CNOT chain CNOT(0,1)..CNOT(8,9): src qubit-bit k = m_k ^ m_{k-1}.
// pre pair-swap (^1 on reg) conditioned at SOURCE lane on parity(lane&0b111011)
// == dest lane bit5 (telescoping), then bpermute gather + reg cycle-chase of
// f(r) = (r ^ (r<<1)) & 31.
__device__ __forceinline__ void chain32(float (&a)[32], int baddr, bool lpar)
{
    #pragma unroll
    for (int k = 0; k < 16; k++) {
        float e0 = a[2*k], o0 = a[2*k+1];
        a[2*k]   = lpar ? o0 : e0;
        a[2*k+1] = lpar ? e0 : o0;
    }
    auto BPf = [&](float v){ return i2f(__builtin_amdgcn_ds_bpermute(baddr, f2i(v))); };
    a[0]  = BPf(a[0]);
    a[16] = BPf(a[16]);
    { float t=a[8];  a[8] =BPf(a[24]); a[24]=BPf(t); }
    { float t=a[2];  a[2] =BPf(a[6]);  a[6] =BPf(a[10]); a[10]=BPf(a[30]); a[30]=BPf(t); }
    { float t=a[4];  a[4] =BPf(a[12]); a[12]=BPf(a[20]); a[20]=BPf(a[28]); a[28]=BPf(t); }
    { float t=a[14]; a[14]=BPf(a[18]); a[18]=BPf(a[22]); a[22]=BPf(a[26]); a[26]=BPf(t); }
    { float t=a[1];  a[1] =BPf(a[3]);  a[3] =BPf(a[5]);  a[5] =BPf(a[15]); a[15]=BPf(a[17]);
      a[17]=BPf(a[19]); a[19]=BPf(a[21]); a[21]=BPf(a[31]); a[31]=BPf(t); }
    { float t=a[7];  a[7] =BPf(a[9]);  a[9] =BPf(a[27]); a[27]=BPf(a[13]); a[13]=BPf(a[23]);
      a[23]=BPf(a[25]); a[25]=BPf(a[11]); a[11]=BPf(a[29]); a[29]=BPf(t); }
}

template<int B>   // B = lane bit hosting this qubit
__device__ __forceinline__ void lane_gate32(float (&ar)[32], float (&ai)[32],
                                            const float* __restrict__ U, int lane)
{
    float u00r=U[0], u00i=U[1], u01r=U[2], u01i=U[3];
    float u10r=U[4], u10i=U[5], u11r=U[6], u11i=U[7];
    bool hi = (lane >> B) & 1;
    float msr = hi ? u11r : u00r, msi = hi ? u11i : u00i;
    float mor = hi ? u10r : u01r, moi = hi ? u10i : u01i;
    #pragma unroll
    for (int r = 0; r < 32; r++){
        float o_r = lx<B>(ar[r]);
        float o_i = lx<B>(ai[r]);
        float nr = msr*ar[r] - msi*ai[r] + mor*o_r - moi*o_i;
        float ni = msr*ai[r] + msi*ar[r] + mor*o_i + moi*o_r;
        ar[r] = nr; ai[r] = ni;
    }
}

template<int B>
__device__ __forceinline__ float st_signed(float v, int lane){
    float t = lx<B>(v);
    return ((lane >> B) & 1) ? (t - v) : (v - t);
}
template<int B>
__device__ __forceinline__ float st_plain(float v){ return v + lx<B>(v); }

// butterfly over lane bits {0,1,3,4,5} in qubit order; first NS stages signed
template<int NS>
__device__ __forceinline__ float zred(float v, int lane){
    if constexpr (NS > 0) v = st_signed<0>(v, lane); else v = st_plain<0>(v);
    if constexpr (NS > 1) v = st_signed<1>(v, lane); else v = st_plain<1>(v);
    if constexpr (NS > 2) v = st_signed<3>(v, lane); else v = st_plain<3>(v);
    if constexpr (NS > 3) v = st_signed<4>(v, lane); else v = st_plain<4>(v);
    if constexpr (NS > 4) v = st_signed<5>(v, lane); else v = st_plain<5>(v);
    return v;
}

__global__ __launch_bounds__(256) void k_qsim(
        const float* __restrict__ x,
        const float* __restrict__ W1, const float* __restrict__ b1,
        const float* __restrict__ W2, const float* __restrict__ b2,
        const float* __restrict__ ws,
        const float* __restrict__ W3, const float* __restrict__ b3,
        const float* __restrict__ W4, const float* __restrict__ b4,
        float* __restrict__ out)
{
    const int lane = threadIdx.x & 63;
    int wid0 = (blockIdx.x * 256 + threadIdx.x) >> 6;
    const int wid = __builtin_amdgcn_readfirstlane(wid0);   // wave = sample pair

    // ---- front MLP for both samples (half-wave each), then per-lane c/s ----
    float cv[10], sv[10];
    {
        const int j = lane & 31;
        const float* xr  = x + (2*wid + (lane >> 5)) * 64;  // uniform per half
        const float* w1r = W1 + j * 64;
        float a = b1[j];
        #pragma unroll
        for (int k = 0; k < 64; k += 4) {
            float4 xv = *reinterpret_cast<const float4*>(xr + k);
            float4 wv = *reinterpret_cast<const float4*>(w1r + k);
            a = fmaf(wv.x, xv.x, a);
            a = fmaf(wv.y, xv.y, a);
            a = fmaf(wv.z, xv.z, a);
            a = fmaf(wv.w, xv.w, a);
        }
        float h = fmaxf(a, 0.0f);

        float tsel = 0.0f;
        #pragma unroll
        for (int i = 0; i < 10; i++) {
            float t = W2[i*32 + j] * h;
            t = st_plain<4>(t);  t = st_plain<3>(t);  t = st_plain<2>(t);
            t = st_plain<1>(t);  t = st_plain<0>(t);  // sum within 32-lane half
            t += b2[i];
            if (j == i) tsel = t;          // lane i: angle i (A); lane 32+i: (B)
        }
        float ang = tanhf(tsel) * 1.5707963267948966f;   // (tanh*pi)*0.5
        float sn, cs;
        __sincosf(ang, &sn, &cs);
        const bool sB = (lane >> 2) & 1;   // sim-phase sample bit
        #pragma unroll
        for (int q = 0; q < 10; q++) {
            float c0 = i2f(__builtin_amdgcn_readlane(f2i(cs), q));
            float c1 = i2f(__builtin_amdgcn_readlane(f2i(cs), 32 + q));
            cv[q] = sB ? c1 : c0;
            float s0 = i2f(__builtin_amdgcn_readlane(f2i(sn), q));
            float s1 = i2f(__builtin_amdgcn_readlane(f2i(sn), 32 + q));
            sv[q] = sB ? s1 : s0;
        }
    }

    float ar[32], ai[32];

    // ---- init: product state with layer-0 1q gates folded in ---------------
    {
        // lane factor over qubits 0..4 (lane bits 0,1,3,4,5)
        float Lr, Li;
        {
            const float* U = ws;
            float v0r = U[0]*cv[0] + U[2]*sv[0], v0i = U[1]*cv[0] + U[3]*sv[0];
            float v1r = U[4]*cv[0] + U[6]*sv[0], v1i = U[5]*cv[0] + U[7]*sv[0];
            bool b = lane & 1;
            Lr = b ? v1r : v0r;  Li = b ? v1i : v0i;
        }
        const int LB[5] = {0, 1, 3, 4, 5};
        #pragma unroll
        for (int q = 1; q < 5; q++) {
            const float* U = ws + q*8;
            float v0r = U[0]*cv[q] + U[2]*sv[q], v0i = U[1]*cv[q] + U[3]*sv[q];
            float v1r = U[4]*cv[q] + U[6]*sv[q], v1i = U[5]*cv[q] + U[7]*sv[q];
            bool b = (lane >> LB[q]) & 1;
            float fr = b ? v1r : v0r, fi = b ? v1i : v0i;
            float nr = Lr*fr - Li*fi;
            float ni = Lr*fi + Li*fr;
            Lr = nr; Li = ni;
        }
        // reg-qubit 2-vectors (qubits 5..9 -> reg bits 0..4)
        float vrq[5][2], viq[5][2];
        #pragma unroll
        for (int q = 5; q < 10; q++) {
            const float* U = ws + q*8;
            vrq[q-5][0] = U[0]*cv[q] + U[2]*sv[q];  viq[q-5][0] = U[1]*cv[q] + U[3]*sv[q];
            vrq[q-5][1] = U[4]*cv[q] + U[6]*sv[q];  viq[q-5][1] = U[5]*cv[q] + U[7]*sv[q];
        }
        // in-place tensor build: ar/ai[r] = Lfac * prod_k v_{5+k}[r_k]
        ar[0] = Lr; ai[0] = Li;
        #pragma unroll
        for (int k = 0; k < 5; k++) {
            const int size = 1 << k;
            #pragma unroll
            for (int i = 0; i < size; i++) {
                float r0 = ar[i], i0 = ai[i];
                ar[i+size] = r0*vrq[k][1] - i0*viq[k][1];
                ai[i+size] = r0*viq[k][1] + i0*vrq[k][1];
                ar[i]      = r0*vrq[k][0] - i0*viq[k][0];
                ai[i]      = r0*viq[k][0] + i0*vrq[k][0];
            }
        }
    }

    // chain constants: src lane bits: s0=L0, s1=L1^L0, s2=L2, s3=L3^L1,
    // s4=L4^L3, s5=L5^L4
    const int q_ = lane;
    const int t1_ = q_ ^ (q_ << 1);
    const int srcl = (q_ & 0b000101) | (t1_ & 0b110010)
                   | ((((q_ >> 3) ^ (q_ >> 1)) & 1) << 3);
    const int  baddr = srcl << 2;
    const bool lpar  = __builtin_popcount(lane & 0b111011) & 1;

    // ---- layers: chain(l-1) then gates(l), l = 1..5 (last chain folded) ----
    #pragma unroll 1
    for (int l = 1; l < 6; ++l) {
        chain32(ar, baddr, lpar);
        chain32(ai, baddr, lpar);
        const float* Ub = ws + l * 80;
        lane_gate32<0>(ar, ai, Ub +  0, lane);   // qubit 0
        lane_gate32<1>(ar, ai, Ub +  8, lane);   // qubit 1
        lane_gate32<3>(ar, ai, Ub + 16, lane);   // qubit 2
        lane_gate32<4>(ar, ai, Ub + 24, lane);   // qubit 3
        lane_gate32<5>(ar, ai, Ub + 32, lane);   // qubit 4
        // reg-bit qubits 5..9
        #pragma unroll
        for (int qq = 0; qq < 5; qq++) {
            const float* U = Ub + (5+qq)*8;
            float u00r=U[0], u00i=U[1], u01r=U[2], u01i=U[3];
            float u10r=U[4], u10i=U[5], u11r=U[6], u11i=U[7];
            const int m = 1 << qq;
            #pragma unroll
            for (int r = 0; r < 32; r++) {
                if (!(r & m)) {
                    const int r2 = r | m;
                    float a0r=ar[r], a0i=ai[r], a1r=ar[r2], a1i=ai[r2];
                    ar[r]  = u00r*a0r - u00i*a0i + u01r*a1r - u01i*a1i;
                    ai[r]  = u00r*a0i + u00i*a0r + u01r*a1i + u01i*a1r;
                    ar[r2] = u10r*a0r - u10i*a0i + u11r*a1r - u11i*a1i;
                    ai[r2] = u10r*a0i + u10i*a0r + u11r*a1i + u11i*a1r;
                }
            }
        }
    }

    // ---- readout: z_i = sum p * (-1)^popcount(idx & prefix_mask_i) ---------
    float p[32];
    #pragma unroll
    for (int r = 0; r < 32; r++) p[r] = ar[r]*ar[r] + ai[r]*ai[r];
    float u[16], d[16];
    #pragma unroll
    for (int k = 0; k < 16; k++) { u[k] = p[2*k] + p[2*k+1]; d[k] = p[2*k] - p[2*k+1]; }
    float S  = (((u[0]+u[1])+(u[2]+u[3])) + ((u[4]+u[5])+(u[6]+u[7])))
             + (((u[8]+u[9])+(u[10]+u[11])) + ((u[12]+u[13])+(u[14]+u[15])));
    float R1 = (((d[0]+d[1])+(d[2]+d[3])) + ((d[4]+d[5])+(d[6]+d[7])))
             + (((d[8]+d[9])+(d[10]+d[11])) + ((d[12]+d[13])+(d[14]+d[15])));
    float e[8];
    #pragma unroll
    for (int k = 0; k < 8; k++) e[k] = d[2*k] - d[2*k+1];
    float R2 = ((e[0]+e[1]) + (e[2]+e[3])) + ((e[4]+e[5]) + (e[6]+e[7]));
    float f4[4];
    #pragma unroll
    for (int k = 0; k < 4; k++) f4[k] = e[2*k] - e[2*k+1];
    float R3 = (f4[0]+f4[1]) + (f4[2]+f4[3]);
    float g0 = f4[0]-f4[1], g1 = f4[2]-f4[3];
    float R4 = g0 + g1;
    float R5 = g0 - g1;

    float z[10];
    z[0] = zred<1>(S,  lane);
    z[1] = zred<2>(S,  lane);
    z[2] = zred<3>(S,  lane);
    z[3] = zred<4>(S,  lane);
    z[4] = zred<5>(S,  lane);
    z[5] = zred<5>(R1, lane);
    z[6] = zred<5>(R2, lane);
    z[7] = zred<5>(R3, lane);
    z[8] = zred<5>(R4, lane);
    z[9] = zred<5>(R5, lane);

    // ---- tail MLP: per-lane (each lane holds its sample's z) ---------------
    float acc0 = b4[0], acc1 = b4[1];
    #pragma unroll
    for (int j2 = 0; j2 < 16; j2++) {
        float a = b3[j2];
        #pragma unroll
        for (int q = 0; q < 10; q++) a = fmaf(W3[j2*10 + q], z[q], a);
        a = fmaxf(a, 0.0f);
        acc0 = fmaf(W4[j2],      a, acc0);
        acc1 = fmaf(W4[16 + j2], a, acc1);
    }
    if ((lane & 0b111011) == 0) {            // lanes 0 (A) and 4 (B)
        int sidx = 2*wid + (lane >> 2);
        reinterpret_cast<float2*>(out)[sidx] = make_float2(acc0, acc1);
    }
}

extern "C" void kernel_launch(void* const* d_in, const int* in_sizes, int n_in,
                              void* d_out, int out_size, void* d_ws, size_t ws_size,
                              hipStream_t stream)
{
    (void)in_sizes; (void)n_in; (void)out_size; (void)ws_size;
    const float* x  = (const float*)d_in[0];
    const float* W1 = (const float*)d_in[1];
    const float* b1 = (const float*)d_in[2];
    const float* W2 = (const float*)d_in[3];
    const float* b2 = (const float*)d_in[4];
    const float* qp = (const float*)d_in[5];
    const float* W3 = (const float*)d_in[6];
    const float* b3 = (const float*)d_in[7];
    const float* W4 = (const float*)d_in[8];
    const float* b4 = (const float*)d_in[9];
    float* ws  = (float*)d_ws;
    float* out = (float*)d_out;

    k_prep<<<1, 64, 0, stream>>>(qp, ws);
    k_qsim<<<2048, 256, 0, stream>>>(x, W1, b1, W2, b2, ws, W3, b3, W4, b4, out);
}

// Round 6
// 206.668 us; speedup vs baseline: 10.3915x; 1.8132x over previous
//
#include <hip/hip_runtime.h>

typedef float vf2 __attribute__((ext_vector_type(2)));

// ---------------------------------------------------------------------------
// helpers: cross-lane primitives
// ---------------------------------------------------------------------------
__device__ __forceinline__ int   f2i(float x){ return __builtin_bit_cast(int, x); }
__device__ __forceinline__ float i2f(int x)  { return __builtin_bit_cast(float, x); }

template<int CTRL>
__device__ __forceinline__ float dppf(float x){
    return i2f(__builtin_amdgcn_mov_dpp(f2i(x), CTRL, 0xF, 0xF, true));
}
template<int PAT>
__device__ __forceinline__ float swzf(float x){
    return i2f(__builtin_amdgcn_ds_swizzle(f2i(x), PAT));
}
// xor32 via permlane32_swap, convention-immune: self-swap returns the two
// 32-half duplicates in some order; partner = r0 + r1 - own.
__device__ __forceinline__ float xor32f(float x){
    unsigned ux = __builtin_bit_cast(unsigned, x);
    auto r = __builtin_amdgcn_permlane32_swap(ux, ux, false, false);
    float a = __builtin_bit_cast(float, (unsigned)r[0]);
    float b = __builtin_bit_cast(float, (unsigned)r[1]);
    return (a + b) - x;
}
#if defined(__has_builtin)
#if __has_builtin(__builtin_amdgcn_permlane16_swap)
#define HAVE_PL16 1
#endif
#endif
__device__ __forceinline__ float xor16f(float x){
#ifdef HAVE_PL16
    unsigned ux = __builtin_bit_cast(unsigned, x);
    auto r = __builtin_amdgcn_permlane16_swap(ux, ux, false, false);
    float a = __builtin_bit_cast(float, (unsigned)r[0]);
    float b = __builtin_bit_cast(float, (unsigned)r[1]);
    return (a + b) - x;
#else
    return swzf<0x401F>(x);
#endif
}
// lane-xor on bit B
template<int B>
__device__ __forceinline__ float lx(float x){
    if constexpr      (B == 0) return dppf<0xB1>(x);    // quad_perm [1,0,3,2]
    else if constexpr (B == 1) return dppf<0x4E>(x);    // quad_perm [2,3,0,1]
    else if constexpr (B == 2) return swzf<0x101F>(x);  // ds_swizzle xor4 (DS)
    else if constexpr (B == 3) return dppf<0x128>(x);   // row_ror:8 == xor8
    else if constexpr (B == 4) return xor16f(x);        // permlane16_swap
    else                       return xor32f(x);        // permlane32_swap
}

// ---------------------------------------------------------------------------
// prep: build 60 fused gate matrices U = RZ*RY*RX from q_params (f32)
// ---------------------------------------------------------------------------
__global__ void k_prep(const float* __restrict__ qp, float* __restrict__ ws)
{
    int t = threadIdx.x;
    if (t >= 60) return;
    int l = t / 10;
    float tx = 0.5f * qp[t*3 + 0];
    float ty = 0.5f * qp[t*3 + 1];
    float tz = 0.5f * qp[t*3 + 2];
    float cx = cosf(tx), sx = sinf(tx);
    float cy = cosf(ty), sy = sinf(ty);
    float cz, sz;
    if (l == 5) { cz = 1.0f; sz = 0.0f; }   // final RZ commutes with Z readout
    else        { cz = cosf(tz); sz = sinf(tz); }
    float m00r =  cy*cx, m00i =  sy*sx;
    float m01r = -sy*cx, m01i = -cy*sx;
    float m10r =  sy*cx, m10i = -cy*sx;
    float m11r =  cy*cx, m11i = -sy*sx;
    float* U = ws + t*8;
    U[0] = m00r*cz + m00i*sz;  U[1] = m00i*cz - m00r*sz;
    U[2] = m01r*cz + m01i*sz;  U[3] = m01i*cz - m01r*sz;
    U[4] = m10r*cz - m10i*sz;  U[5] = m10i*cz + m10r*sz;
    U[6] = m11r*cz - m11i*sz;  U[7] = m11i*cz + m11r*sz;
}

// ---------------------------------------------------------------------------
// quantum sim: 1 wave = 1 sample; qubit q<6 -> lane bit q, q>=6 -> reg bit q-6
// state: 16 complex amps packed as vf2 pr[8], pi[8]  (pack k = regs 2k, 2k+1)
// ---------------------------------------------------------------------------

// composed CNOT chain CNOT(0,1)..CNOT(8,9): lane gather + reg cycle-chase
__device__ __forceinline__ void chainP(vf2 (&a)[8], int baddr, bool lpar)
{
    #pragma unroll
    for (int k = 0; k < 8; k++) {      // conditional intra-pack swap (^1 on reg)
        vf2 v  = a[k];
        vf2 sw = __builtin_shufflevector(v, v, 1, 0);
        a[k] = lpar ? sw : v;
    }
    auto BPf = [&](float v){ return i2f(__builtin_amdgcn_ds_bpermute(baddr, f2i(v))); };
#define A_(r) a[(r)>>1][(r)&1]
    // reg map f cycles: {0},{8},(1,3,5,15),(2,6,10,14),(4,12),(7,9,11,13)
    A_(0) = BPf(A_(0));
    A_(8) = BPf(A_(8));
    { float t=A_(1); A_(1)=BPf(A_(3));  A_(3)=BPf(A_(5));  A_(5)=BPf(A_(15)); A_(15)=BPf(t); }
    { float t=A_(2); A_(2)=BPf(A_(6));  A_(6)=BPf(A_(10)); A_(10)=BPf(A_(14)); A_(14)=BPf(t); }
    { float t=A_(4); A_(4)=BPf(A_(12)); A_(12)=BPf(t); }
    { float t=A_(7); A_(7)=BPf(A_(9));  A_(9)=BPf(A_(11)); A_(11)=BPf(A_(13)); A_(13)=BPf(t); }
#undef A_
}

template<int B>
__device__ __forceinline__ void lane_gateP(vf2 (&pr)[8], vf2 (&pi)[8],
                                           const float* __restrict__ U, int lane)
{
    float u00r=U[0], u00i=U[1], u01r=U[2], u01i=U[3];
    float u10r=U[4], u10i=U[5], u11r=U[6], u11i=U[7];
    bool hi = (lane >> B) & 1;
    float msr = hi ? u11r : u00r, msi = hi ? u11i : u00i;
    float mor = hi ? u10r : u01r, moi = hi ? u10i : u01i;
    #pragma unroll
    for (int k = 0; k < 8; k++){
        vf2 orr, oii;
        orr.x = lx<B>(pr[k].x);  orr.y = lx<B>(pr[k].y);
        oii.x = lx<B>(pi[k].x);  oii.y = lx<B>(pi[k].y);
        vf2 nr = msr*pr[k] - msi*pi[k] + mor*orr - moi*oii;
        vf2 ni = msr*pi[k] + msi*pr[k] + mor*oii + moi*orr;
        pr[k] = nr; pi[k] = ni;
    }
}

// reg-bit gate with partner in a different pack (qubits 7,8,9 -> M2 = 1,2,4)
template<int M2>
__device__ __forceinline__ void reg_gateP(vf2 (&pr)[8], vf2 (&pi)[8],
                                          const float* __restrict__ U)
{
    float u00r=U[0], u00i=U[1], u01r=U[2], u01i=U[3];
    float u10r=U[4], u10i=U[5], u11r=U[6], u11i=U[7];
    #pragma unroll
    for (int k = 0; k < 8; k++) if (!(k & M2)) {
        const int k2 = k | M2;
        vf2 A0r=pr[k], A0i=pi[k], A1r=pr[k2], A1i=pi[k2];
        pr[k]  = u00r*A0r - u00i*A0i + u01r*A1r - u01i*A1i;
        pi[k]  = u00r*A0i + u00i*A0r + u01r*A1i + u01i*A1r;
        pr[k2] = u10r*A0r - u10i*A0i + u11r*A1r - u11i*A1i;
        pi[k2] = u10r*A0i + u10i*A0r + u11r*A1i + u11i*A1r;
    }
}

template<int B>
__device__ __forceinline__ float st_signed(float v, int lane){
    float t = lx<B>(v);
    return ((lane >> B) & 1) ? (t - v) : (v - t);
}
template<int B>
__device__ __forceinline__ float st_plain(float v){ return v + lx<B>(v); }

template<int I>
__device__ __forceinline__ float z_mixed(float S, int lane){
    float v = st_signed<0>(S, lane);
    if constexpr (I >= 1) v = st_signed<1>(v, lane); else v = st_plain<1>(v);
    if constexpr (I >= 2) v = st_signed<2>(v, lane); else v = st_plain<2>(v);
    if constexpr (I >= 3) v = st_signed<3>(v, lane); else v = st_plain<3>(v);
    if constexpr (I >= 4) v = st_signed<4>(v, lane); else v = st_plain<4>(v);
    if constexpr (I >= 5) v = st_signed<5>(v, lane); else v = st_plain<5>(v);
    return v;
}

__global__ __launch_bounds__(256) void k_qsim(
        const float* __restrict__ x,
        const float* __restrict__ W1, const float* __restrict__ b1,
        const float* __restrict__ W2, const float* __restrict__ b2,
        const float* __restrict__ ws,
        const float* __restrict__ W3, const float* __restrict__ b3,
        const float* __restrict__ W4, const float* __restrict__ b4,
        float* __restrict__ out)
{
    const int lane = threadIdx.x & 63;
    int wid = (blockIdx.x * 256 + threadIdx.x) >> 6;
    const int s = __builtin_amdgcn_readfirstlane(wid);

    // ---- fused front MLP: x(64) -> relu h(32) -> 10 angles -> cos/sin ------
    float cv[10], sv[10];
    {
        const float* xr  = x + s * 64;            // wave-uniform -> s_loads
        const int j = lane & 31;                  // lanes j and j+32 do row j
        const float* w1r = W1 + j * 64;
        float a = b1[j];
        #pragma unroll
        for (int k = 0; k < 64; k += 4) {
            float4 xv = *reinterpret_cast<const float4*>(xr + k);
            float4 wv = *reinterpret_cast<const float4*>(w1r + k);
            a = fmaf(wv.x, xv.x, a);
            a = fmaf(wv.y, xv.y, a);
            a = fmaf(wv.z, xv.z, a);
            a = fmaf(wv.w, xv.w, a);
        }
        float h = fmaxf(a, 0.0f);

        float tsel = 0.0f;
        #pragma unroll
        for (int i = 0; i < 10; i++) {
            float t = W2[i*32 + j] * h;
            t = st_plain<4>(t);  t = st_plain<3>(t);  t = st_plain<2>(t);
            t = st_plain<1>(t);  t = st_plain<0>(t);  // sum within 32-lane half
            t += b2[i];
            if (lane == i) tsel = t;               // lane i keeps angle i
        }
        float ang = tanhf(tsel) * 1.5707963267948966f;   // (tanh*pi)*0.5
        float sA, cA;
        __sincosf(ang, &sA, &cA);
        #pragma unroll
        for (int q = 0; q < 10; q++) {
            cv[q] = i2f(__builtin_amdgcn_readlane(f2i(cA), q));
            sv[q] = i2f(__builtin_amdgcn_readlane(f2i(sA), q));
        }
    }

    vf2 pr[8], pi[8];
#define ARr(r) pr[(r)>>1][(r)&1]
#define AIr(r) pi[(r)>>1][(r)&1]

    // ---- init: RY-encoding product state with layer-0 1q gates folded in ---
    {
        const float* U0 = ws;
        float Lr, Li;
        {
            float v0r = U0[0]*cv[0] + U0[2]*sv[0], v0i = U0[1]*cv[0] + U0[3]*sv[0];
            float v1r = U0[4]*cv[0] + U0[6]*sv[0], v1i = U0[5]*cv[0] + U0[7]*sv[0];
            bool b = lane & 1;
            Lr = b ? v1r : v0r;  Li = b ? v1i : v0i;
        }
        #pragma unroll
        for (int q = 1; q < 6; q++) {
            const float* U = U0 + q*8;
            float v0r = U[0]*cv[q] + U[2]*sv[q], v0i = U[1]*cv[q] + U[3]*sv[q];
            float v1r = U[4]*cv[q] + U[6]*sv[q], v1i = U[5]*cv[q] + U[7]*sv[q];
            bool b = (lane >> q) & 1;
            float fr = b ? v1r : v0r, fi = b ? v1i : v0i;
            float nr = Lr*fr - Li*fi;
            float ni = Lr*fi + Li*fr;
            Lr = nr; Li = ni;
        }
        float vr[4][2], vi[4][2];
        #pragma unroll
        for (int q = 6; q < 10; q++) {
            const float* U = U0 + q*8;
            vr[q-6][0] = U[0]*cv[q] + U[2]*sv[q];  vi[q-6][0] = U[1]*cv[q] + U[3]*sv[q];
            vr[q-6][1] = U[4]*cv[q] + U[6]*sv[q];  vi[q-6][1] = U[5]*cv[q] + U[7]*sv[q];
        }
        float t67r[4], t67i[4], t89r[4], t89i[4];
        #pragma unroll
        for (int m = 0; m < 4; m++) {
            int b0 = m & 1, b1i = (m >> 1) & 1;
            t67r[m] = vr[0][b0]*vr[1][b1i] - vi[0][b0]*vi[1][b1i];
            t67i[m] = vr[0][b0]*vi[1][b1i] + vi[0][b0]*vr[1][b1i];
            t89r[m] = vr[2][b0]*vr[3][b1i] - vi[2][b0]*vi[3][b1i];
            t89i[m] = vr[2][b0]*vi[3][b1i] + vi[2][b0]*vr[3][b1i];
        }
        #pragma unroll
        for (int r = 0; r < 16; r++) {
            const int lo = r & 3, hi = r >> 2;
            float prr = t67r[lo]*t89r[hi] - t67i[lo]*t89i[hi];
            float pii = t67r[lo]*t89i[hi] + t67i[lo]*t89r[hi];
            ARr(r) = Lr*prr - Li*pii;
            AIr(r) = Lr*pii + Li*prr;
        }
    }

    const int  baddr = ((lane ^ (lane << 1)) & 63) << 2;
    const bool lpar  = __builtin_popcount(lane & 63) & 1;

    // ---- layers: chain(l-1) then gates(l), l = 1..5 (last chain folded) ----
    #pragma unroll 1
    for (int l = 1; l < 6; ++l) {
        chainP(pr, baddr, lpar);
        chainP(pi, baddr, lpar);
        const float* Ub = ws + l * 80;
        lane_gateP<0>(pr, pi, Ub +  0, lane);
        lane_gateP<1>(pr, pi, Ub +  8, lane);
        lane_gateP<2>(pr, pi, Ub + 16, lane);
        lane_gateP<3>(pr, pi, Ub + 24, lane);
        lane_gateP<4>(pr, pi, Ub + 32, lane);
        lane_gateP<5>(pr, pi, Ub + 40, lane);
        // qubit 6 (reg bit 0): intra-pack 2x2 complex mix (scalar halves)
        {
            const float* U = Ub + 48;
            float u00r=U[0], u00i=U[1], u01r=U[2], u01i=U[3];
            float u10r=U[4], u10i=U[5], u11r=U[6], u11i=U[7];
            #pragma unroll
            for (int k = 0; k < 8; k++) {
                float a0r=pr[k].x, a0i=pi[k].x, a1r=pr[k].y, a1i=pi[k].y;
                pr[k].x = u00r*a0r - u00i*a0i + u01r*a1r - u01i*a1i;
                pi[k].x = u00r*a0i + u00i*a0r + u01r*a1i + u01i*a1r;
                pr[k].y = u10r*a0r - u10i*a0i + u11r*a1r - u11i*a1i;
                pi[k].y = u10r*a0i + u10i*a0r + u11r*a1i + u11i*a1r;
            }
        }
        reg_gateP<1>(pr, pi, Ub + 56);   // qubit 7
        reg_gateP<2>(pr, pi, Ub + 64);   // qubit 8
        reg_gateP<4>(pr, pi, Ub + 72);   // qubit 9
    }

    // ---- readout: z_i = sum p * (-1)^popcount(idx & prefix_mask_i) ---------
    float u[8], d[8];
    #pragma unroll
    for (int k = 0; k < 8; k++) {
        vf2 P = pr[k]*pr[k] + pi[k]*pi[k];
        u[k] = P.x + P.y;
        d[k] = P.x - P.y;
    }
    float S  = ((u[0]+u[1]) + (u[2]+u[3])) + ((u[4]+u[5]) + (u[6]+u[7]));
    float T0 = ((d[0]+d[1]) + (d[2]+d[3])) + ((d[4]+d[5]) + (d[6]+d[7]));
    float e0 = d[0]-d[1], e1 = d[2]-d[3], e2 = d[4]-d[5], e3 = d[6]-d[7];
    float T1 = (e0+e1) + (e2+e3);
    float f0 = e0-e1, f1 = e2-e3;
    float T2 = f0 + f1;
    float T3 = f0 - f1;

    float z[10];
    z[0] = z_mixed<0>(S, lane);
    z[1] = z_mixed<1>(S, lane);
    z[2] = z_mixed<2>(S, lane);
    z[3] = z_mixed<3>(S, lane);
    z[4] = z_mixed<4>(S, lane);
    z[5] = z_mixed<5>(S, lane);
    z[6] = z_mixed<5>(T0, lane);
    z[7] = z_mixed<5>(T1, lane);
    z[8] = z_mixed<5>(T2, lane);
    z[9] = z_mixed<5>(T3, lane);

    // ---- tail MLP: z -> relu(16) -> 2 (redundant per lane, lane0 stores) ---
    float acc0 = b4[0], acc1 = b4[1];
    #pragma unroll
    for (int j2 = 0; j2 < 16; j2++) {
        float a = b3[j2];
        #pragma unroll
        for (int q = 0; q < 10; q++) a = fmaf(W3[j2*10 + q], z[q], a);
        a = fmaxf(a, 0.0f);
        acc0 = fmaf(W4[j2],      a, acc0);
        acc1 = fmaf(W4[16 + j2], a, acc1);
    }
    if (lane == 0) {
        reinterpret_cast<float2*>(out)[s] = make_float2(acc0, acc1);
    }
#undef ARr
#undef AIr
}

extern "C" void kernel_launch(void* const* d_in, const int* in_sizes, int n_in,
                              void* d_out, int out_size, void* d_ws, size_t ws_size,
                              hipStream_t stream)
{
    (void)in_sizes; (void)n_in; (void)out_size; (void)ws_size;
    const float* x  = (const float*)d_in[0];
    const float* W1 = (const float*)d_in[1];
    const float* b1 = (const float*)d_in[2];
    const float* W2 = (const float*)d_in[3];
    const float* b2 = (const float*)d_in[4];
    const float* qp = (const float*)d_in[5];
    const float* W3 = (const float*)d_in[6];
    const float* b3 = (const float*)d_in[7];
    const float* W4 = (const float*)d_in[8];
    const float* b4 = (const float*)d_in[9];
    float* ws  = (float*)d_ws;
    float* out = (float*)d_out;

    k_prep<<<1, 64, 0, stream>>>(qp, ws);
    k_qsim<<<4096, 256, 0, stream>>>(x, W1, b1, W2, b2, ws, W3, b3, W4, b4, out);
}

// Round 7
// 203.632 us; speedup vs baseline: 10.5464x; 1.0149x over previous
//
#include <hip/hip_runtime.h>

typedef float vf2 __attribute__((ext_vector_type(2)));

// ---------------------------------------------------------------------------
// helpers: cross-lane primitives
// ---------------------------------------------------------------------------
__device__ __forceinline__ int   f2i(float x){ return __builtin_bit_cast(int, x); }
__device__ __forceinline__ float i2f(int x)  { return __builtin_bit_cast(float, x); }

template<int CTRL>
__device__ __forceinline__ float dppf(float x){
    return i2f(__builtin_amdgcn_mov_dpp(f2i(x), CTRL, 0xF, 0xF, true));
}
template<int PAT>
__device__ __forceinline__ float swzf(float x){
    return i2f(__builtin_amdgcn_ds_swizzle(f2i(x), PAT));
}
// xor32 via permlane32_swap, convention-immune: self-swap returns the two
// 32-half duplicates in some order; partner = r0 + r1 - own.
__device__ __forceinline__ float xor32f(float x){
    unsigned ux = __builtin_bit_cast(unsigned, x);
    auto r = __builtin_amdgcn_permlane32_swap(ux, ux, false, false);
    float a = __builtin_bit_cast(float, (unsigned)r[0]);
    float b = __builtin_bit_cast(float, (unsigned)r[1]);
    return (a + b) - x;
}
// pair-sum over lane-bit 5: x + partner  (2 ops, convention-immune)
__device__ __forceinline__ float sum32(float x){
    unsigned ux = __builtin_bit_cast(unsigned, x);
    auto r = __builtin_amdgcn_permlane32_swap(ux, ux, false, false);
    float a = __builtin_bit_cast(float, (unsigned)r[0]);
    float b = __builtin_bit_cast(float, (unsigned)r[1]);
    return a + b;
}
#if defined(__has_builtin)
#if __has_builtin(__builtin_amdgcn_permlane16_swap)
#define HAVE_PL16 1
#endif
#endif
__device__ __forceinline__ float xor16f(float x){
#ifdef HAVE_PL16
    unsigned ux = __builtin_bit_cast(unsigned, x);
    auto r = __builtin_amdgcn_permlane16_swap(ux, ux, false, false);
    float a = __builtin_bit_cast(float, (unsigned)r[0]);
    float b = __builtin_bit_cast(float, (unsigned)r[1]);
    return (a + b) - x;
#else
    return swzf<0x401F>(x);
#endif
}
// pair-sum over lane-bit 4
__device__ __forceinline__ float sum16(float x){
#ifdef HAVE_PL16
    unsigned ux = __builtin_bit_cast(unsigned, x);
    auto r = __builtin_amdgcn_permlane16_swap(ux, ux, false, false);
    float a = __builtin_bit_cast(float, (unsigned)r[0]);
    float b = __builtin_bit_cast(float, (unsigned)r[1]);
    return a + b;
#else
    return x + swzf<0x401F>(x);
#endif
}
// lane-xor on bit B
template<int B>
__device__ __forceinline__ float lx(float x){
    if constexpr      (B == 0) return dppf<0xB1>(x);    // quad_perm [1,0,3,2]
    else if constexpr (B == 1) return dppf<0x4E>(x);    // quad_perm [2,3,0,1]
    else if constexpr (B == 2) return swzf<0x101F>(x);  // ds_swizzle xor4 (DS)
    else if constexpr (B == 3) return dppf<0x128>(x);   // row_ror:8 == xor8
    else if constexpr (B == 4) return xor16f(x);        // permlane16_swap
    else                       return xor32f(x);        // permlane32_swap
}

// ---------------------------------------------------------------------------
// prep: build 60 fused gate matrices U = RZ*RY*RX from q_params (f32)
// ---------------------------------------------------------------------------
__global__ void k_prep(const float* __restrict__ qp, float* __restrict__ ws)
{
    int t = threadIdx.x;
    if (t >= 60) return;
    int l = t / 10;
    float tx = 0.5f * qp[t*3 + 0];
    float ty = 0.5f * qp[t*3 + 1];
    float tz = 0.5f * qp[t*3 + 2];
    float cx = cosf(tx), sx = sinf(tx);
    float cy = cosf(ty), sy = sinf(ty);
    float cz, sz;
    if (l == 5) { cz = 1.0f; sz = 0.0f; }   // final RZ commutes with Z readout
    else        { cz = cosf(tz); sz = sinf(tz); }
    float m00r =  cy*cx, m00i =  sy*sx;
    float m01r = -sy*cx, m01i = -cy*sx;
    float m10r =  sy*cx, m10i = -cy*sx;
    float m11r =  cy*cx, m11i = -sy*sx;
    float* U = ws + t*8;
    U[0] = m00r*cz + m00i*sz;  U[1] = m00i*cz - m00r*sz;
    U[2] = m01r*cz + m01i*sz;  U[3] = m01i*cz - m01r*sz;
    U[4] = m10r*cz - m10i*sz;  U[5] = m10i*cz + m10r*sz;
    U[6] = m11r*cz - m11i*sz;  U[7] = m11i*cz + m11r*sz;
}

// ---------------------------------------------------------------------------
// quantum sim: 1 wave = 1 sample; qubit q<6 -> lane bit q, q>=6 -> reg bit q-6
// state: 16 complex amps packed as vf2 pr[8], pi[8]  (pack k = regs 2k, 2k+1)
// ---------------------------------------------------------------------------

// composed CNOT chain CNOT(0,1)..CNOT(8,9): lane gather + reg cycle-chase
__device__ __forceinline__ void chainP(vf2 (&a)[8], int baddr, bool lpar)
{
    #pragma unroll
    for (int k = 0; k < 8; k++) {      // conditional intra-pack swap (^1 on reg)
        vf2 v  = a[k];
        vf2 sw = __builtin_shufflevector(v, v, 1, 0);
        a[k] = lpar ? sw : v;
    }
    auto BPf = [&](float v){ return i2f(__builtin_amdgcn_ds_bpermute(baddr, f2i(v))); };
#define A_(r) a[(r)>>1][(r)&1]
    // reg map f cycles: {0},{8},(1,3,5,15),(2,6,10,14),(4,12),(7,9,11,13)
    A_(0) = BPf(A_(0));
    A_(8) = BPf(A_(8));
    { float t=A_(1); A_(1)=BPf(A_(3));  A_(3)=BPf(A_(5));  A_(5)=BPf(A_(15)); A_(15)=BPf(t); }
    { float t=A_(2); A_(2)=BPf(A_(6));  A_(6)=BPf(A_(10)); A_(10)=BPf(A_(14)); A_(14)=BPf(t); }
    { float t=A_(4); A_(4)=BPf(A_(12)); A_(12)=BPf(t); }
    { float t=A_(7); A_(7)=BPf(A_(9));  A_(9)=BPf(A_(11)); A_(11)=BPf(A_(13)); A_(13)=BPf(t); }
#undef A_
}

// gate on lane bit B (B in {0,1,2,3}: direct partner via dpp/swizzle)
template<int B>
__device__ __forceinline__ void lane_gateP(vf2 (&pr)[8], vf2 (&pi)[8],
                                           const float* __restrict__ U, int lane)
{
    float u00r=U[0], u00i=U[1], u01r=U[2], u01i=U[3];
    float u10r=U[4], u10i=U[5], u11r=U[6], u11i=U[7];
    bool hi = (lane >> B) & 1;
    float msr = hi ? u11r : u00r, msi = hi ? u11i : u00i;
    float mor = hi ? u10r : u01r, moi = hi ? u10i : u01i;
    #pragma unroll
    for (int k = 0; k < 8; k++){
        vf2 orr, oii;
        orr.x = lx<B>(pr[k].x);  orr.y = lx<B>(pr[k].y);
        oii.x = lx<B>(pi[k].x);  oii.y = lx<B>(pi[k].y);
        vf2 nr = msr*pr[k] - msi*pi[k] + mor*orr - moi*oii;
        vf2 ni = msr*pi[k] + msi*pr[k] + mor*oii + moi*orr;
        pr[k] = nr; pi[k] = ni;
    }
}

// gate on lane bit B (B in {4,5}): pair-sum form, convention-immune.
// S = a + partner; new = (ms-mo)*a + mo*S.
template<int B>
__device__ __forceinline__ void lane_gateS(vf2 (&pr)[8], vf2 (&pi)[8],
                                           const float* __restrict__ U, int lane)
{
    float u00r=U[0], u00i=U[1], u01r=U[2], u01i=U[3];
    float u10r=U[4], u10i=U[5], u11r=U[6], u11i=U[7];
    bool hi = (lane >> B) & 1;
    float msr = hi ? u11r : u00r, msi = hi ? u11i : u00i;
    float mor = hi ? u10r : u01r, moi = hi ? u10i : u01i;
    float dsr = msr - mor, dsi = msi - moi;
    #pragma unroll
    for (int k = 0; k < 8; k++){
        vf2 Sr, Si;
        if constexpr (B == 4) {
            Sr.x = sum16(pr[k].x);  Sr.y = sum16(pr[k].y);
            Si.x = sum16(pi[k].x);  Si.y = sum16(pi[k].y);
        } else {
            Sr.x = sum32(pr[k].x);  Sr.y = sum32(pr[k].y);
            Si.x = sum32(pi[k].x);  Si.y = sum32(pi[k].y);
        }
        vf2 nr = dsr*pr[k] - dsi*pi[k] + mor*Sr - moi*Si;
        vf2 ni = dsr*pi[k] + dsi*pr[k] + mor*Si + moi*Sr;
        pr[k] = nr; pi[k] = ni;
    }
}

// reg-bit gate with partner in a different pack (qubits 7,8,9 -> M2 = 1,2,4)
template<int M2>
__device__ __forceinline__ void reg_gateP(vf2 (&pr)[8], vf2 (&pi)[8],
                                          const float* __restrict__ U)
{
    float u00r=U[0], u00i=U[1], u01r=U[2], u01i=U[3];
    float u10r=U[4], u10i=U[5], u11r=U[6], u11i=U[7];
    #pragma unroll
    for (int k = 0; k < 8; k++) if (!(k & M2)) {
        const int k2 = k | M2;
        vf2 A0r=pr[k], A0i=pi[k], A1r=pr[k2], A1i=pi[k2];
        pr[k]  = u00r*A0r - u00i*A0i + u01r*A1r - u01i*A1i;
        pi[k]  = u00r*A0i + u00i*A0r + u01r*A1i + u01i*A1r;
        pr[k2] = u10r*A0r - u10i*A0i + u11r*A1r - u11i*A1i;
        pi[k2] = u10r*A0i + u10i*A0r + u11r*A1i + u11i*A1r;
    }
}

template<int B>
__device__ __forceinline__ float st_signed(float v, int lane){
    float t = lx<B>(v);
    return ((lane >> B) & 1) ? (t - v) : (v - t);
}
template<int B>
__device__ __forceinline__ float st_plain(float v){
    if constexpr (B == 4) return sum16(v);
    else if constexpr (B == 5) return sum32(v);
    else return v + lx<B>(v);
}

template<int I>
__device__ __forceinline__ float z_mixed(float S, int lane){
    float v = st_signed<0>(S, lane);
    if constexpr (I >= 1) v = st_signed<1>(v, lane); else v = st_plain<1>(v);
    if constexpr (I >= 2) v = st_signed<2>(v, lane); else v = st_plain<2>(v);
    if constexpr (I >= 3) v = st_signed<3>(v, lane); else v = st_plain<3>(v);
    if constexpr (I >= 4) v = st_signed<4>(v, lane); else v = st_plain<4>(v);
    if constexpr (I >= 5) v = st_signed<5>(v, lane); else v = st_plain<5>(v);
    return v;
}

__global__ __launch_bounds__(256)
__attribute__((amdgpu_waves_per_eu(5, 8)))
void k_qsim(
        const float* __restrict__ x,
        const float* __restrict__ W1, const float* __restrict__ b1,
        const float* __restrict__ W2, const float* __restrict__ b2,
        const float* __restrict__ ws,
        const float* __restrict__ W3, const float* __restrict__ b3,
        const float* __restrict__ W4, const float* __restrict__ b4,
        float* __restrict__ out)
{
    const int lane = threadIdx.x & 63;
    int wid = (blockIdx.x * 256 + threadIdx.x) >> 6;
    const int s = __builtin_amdgcn_readfirstlane(wid);

    // ---- fused front MLP: x(64) -> relu h(32) -> 10 angles -> cos/sin ------
    float cv[10], sv[10];
    {
        const float* xr  = x + s * 64;            // wave-uniform -> s_loads
        const int j = lane & 31;                  // lanes j and j+32 do row j
        const float* w1r = W1 + j * 64;
        float a = b1[j];
        #pragma unroll
        for (int k = 0; k < 64; k += 4) {
            float4 xv = *reinterpret_cast<const float4*>(xr + k);
            float4 wv = *reinterpret_cast<const float4*>(w1r + k);
            a = fmaf(wv.x, xv.x, a);
            a = fmaf(wv.y, xv.y, a);
            a = fmaf(wv.z, xv.z, a);
            a = fmaf(wv.w, xv.w, a);
        }
        float h = fmaxf(a, 0.0f);

        float tsel = 0.0f;
        #pragma unroll
        for (int i = 0; i < 10; i++) {
            float t = W2[i*32 + j] * h;
            t = st_plain<4>(t);  t = st_plain<3>(t);  t = st_plain<2>(t);
            t = st_plain<1>(t);  t = st_plain<0>(t);  // sum within 32-lane half
            t += b2[i];
            if (lane == i) tsel = t;               // lane i keeps angle i
        }
        float ang = tanhf(tsel) * 1.5707963267948966f;   // (tanh*pi)*0.5
        float sA, cA;
        __sincosf(ang, &sA, &cA);
        #pragma unroll
        for (int q = 0; q < 10; q++) {
            cv[q] = i2f(__builtin_amdgcn_readlane(f2i(cA), q));
            sv[q] = i2f(__builtin_amdgcn_readlane(f2i(sA), q));
        }
    }

    vf2 pr[8], pi[8];
#define ARr(r) pr[(r)>>1][(r)&1]
#define AIr(r) pi[(r)>>1][(r)&1]

    // ---- init: RY-encoding product state with layer-0 1q gates folded in ---
    {
        const float* U0 = ws;
        float Lr, Li;
        {
            float v0r = U0[0]*cv[0] + U0[2]*sv[0], v0i = U0[1]*cv[0] + U0[3]*sv[0];
            float v1r = U0[4]*cv[0] + U0[6]*sv[0], v1i = U0[5]*cv[0] + U0[7]*sv[0];
            bool b = lane & 1;
            Lr = b ? v1r : v0r;  Li = b ? v1i : v0i;
        }
        #pragma unroll
        for (int q = 1; q < 6; q++) {
            const float* U = U0 + q*8;
            float v0r = U[0]*cv[q] + U[2]*sv[q], v0i = U[1]*cv[q] + U[3]*sv[q];
            float v1r = U[4]*cv[q] + U[6]*sv[q], v1i = U[5]*cv[q] + U[7]*sv[q];
            bool b = (lane >> q) & 1;
            float fr = b ? v1r : v0r, fi = b ? v1i : v0i;
            float nr = Lr*fr - Li*fi;
            float ni = Lr*fi + Li*fr;
            Lr = nr; Li = ni;
        }
        float vr[4][2], vi[4][2];
        #pragma unroll
        for (int q = 6; q < 10; q++) {
            const float* U = U0 + q*8;
            vr[q-6][0] = U[0]*cv[q] + U[2]*sv[q];  vi[q-6][0] = U[1]*cv[q] + U[3]*sv[q];
            vr[q-6][1] = U[4]*cv[q] + U[6]*sv[q];  vi[q-6][1] = U[5]*cv[q] + U[7]*sv[q];
        }
        float t67r[4], t67i[4], t89r[4], t89i[4];
        #pragma unroll
        for (int m = 0; m < 4; m++) {
            int b0 = m & 1, b1i = (m >> 1) & 1;
            t67r[m] = vr[0][b0]*vr[1][b1i] - vi[0][b0]*vi[1][b1i];
            t67i[m] = vr[0][b0]*vi[1][b1i] + vi[0][b0]*vr[1][b1i];
            t89r[m] = vr[2][b0]*vr[3][b1i] - vi[2][b0]*vi[3][b1i];
            t89i[m] = vr[2][b0]*vi[3][b1i] + vi[2][b0]*vr[3][b1i];
        }
        #pragma unroll
        for (int r = 0; r < 16; r++) {
            const int lo = r & 3, hi = r >> 2;
            float prr = t67r[lo]*t89r[hi] - t67i[lo]*t89i[hi];
            float pii = t67r[lo]*t89i[hi] + t67i[lo]*t89r[hi];
            ARr(r) = Lr*prr - Li*pii;
            AIr(r) = Lr*pii + Li*prr;
        }
    }

    const int  baddr = ((lane ^ (lane << 1)) & 63) << 2;
    const bool lpar  = __builtin_popcount(lane & 63) & 1;

    // ---- layers: chain(l-1) then gates(l), l = 1..5 (last chain folded) ----
    #pragma unroll 1
    for (int l = 1; l < 6; ++l) {
        chainP(pr, baddr, lpar);
        chainP(pi, baddr, lpar);
        const float* Ub = ws + l * 80;
        lane_gateP<0>(pr, pi, Ub +  0, lane);
        lane_gateP<1>(pr, pi, Ub +  8, lane);
        lane_gateP<2>(pr, pi, Ub + 16, lane);
        lane_gateP<3>(pr, pi, Ub + 24, lane);
        lane_gateS<4>(pr, pi, Ub + 32, lane);
        lane_gateS<5>(pr, pi, Ub + 40, lane);
        // qubit 6 (reg bit 0): intra-pack 2x2 complex mix (scalar halves)
        {
            const float* U = Ub + 48;
            float u00r=U[0], u00i=U[1], u01r=U[2], u01i=U[3];
            float u10r=U[4], u10i=U[5], u11r=U[6], u11i=U[7];
            #pragma unroll
            for (int k = 0; k < 8; k++) {
                float a0r=pr[k].x, a0i=pi[k].x, a1r=pr[k].y, a1i=pi[k].y;
                pr[k].x = u00r*a0r - u00i*a0i + u01r*a1r - u01i*a1i;
                pi[k].x = u00r*a0i + u00i*a0r + u01r*a1i + u01i*a1r;
                pr[k].y = u10r*a0r - u10i*a0i + u11r*a1r - u11i*a1i;
                pi[k].y = u10r*a0i + u10i*a0r + u11r*a1i + u11i*a1r;
            }
        }
        reg_gateP<1>(pr, pi, Ub + 56);   // qubit 7
        reg_gateP<2>(pr, pi, Ub + 64);   // qubit 8
        reg_gateP<4>(pr, pi, Ub + 72);   // qubit 9
    }

    // ---- readout: z_i = sum p * (-1)^popcount(idx & prefix_mask_i) ---------
    float u[8], d[8];
    #pragma unroll
    for (int k = 0; k < 8; k++) {
        vf2 P = pr[k]*pr[k] + pi[k]*pi[k];
        u[k] = P.x + P.y;
        d[k] = P.x - P.y;
    }
    float S  = ((u[0]+u[1]) + (u[2]+u[3])) + ((u[4]+u[5]) + (u[6]+u[7]));
    float T0 = ((d[0]+d[1]) + (d[2]+d[3])) + ((d[4]+d[5]) + (d[6]+d[7]));
    float e0 = d[0]-d[1], e1 = d[2]-d[3], e2 = d[4]-d[5], e3 = d[6]-d[7];
    float T1 = (e0+e1) + (e2+e3);
    float f0 = e0-e1, f1 = e2-e3;
    float T2 = f0 + f1;
    float T3 = f0 - f1;

    float z[10];
    z[0] = z_mixed<0>(S, lane);
    z[1] = z_mixed<1>(S, lane);
    z[2] = z_mixed<2>(S, lane);
    z[3] = z_mixed<3>(S, lane);
    z[4] = z_mixed<4>(S, lane);
    z[5] = z_mixed<5>(S, lane);
    z[6] = z_mixed<5>(T0, lane);
    z[7] = z_mixed<5>(T1, lane);
    z[8] = z_mixed<5>(T2, lane);
    z[9] = z_mixed<5>(T3, lane);

    // ---- tail MLP: z -> relu(16) -> 2 (redundant per lane, lane0 stores) ---
    float acc0 = b4[0], acc1 = b4[1];
    #pragma unroll
    for (int j2 = 0; j2 < 16; j2++) {
        float a = b3[j2];
        #pragma unroll
        for (int q = 0; q < 10; q++) a = fmaf(W3[j2*10 + q], z[q], a);
        a = fmaxf(a, 0.0f);
        acc0 = fmaf(W4[j2],      a, acc0);
        acc1 = fmaf(W4[16 + j2], a, acc1);
    }
    if (lane == 0) {
        reinterpret_cast<float2*>(out)[s] = make_float2(acc0, acc1);
    }
#undef ARr
#undef AIr
}

extern "C" void kernel_launch(void* const* d_in, const int* in_sizes, int n_in,
                              void* d_out, int out_size, void* d_ws, size_t ws_size,
                              hipStream_t stream)
{
    (void)in_sizes; (void)n_in; (void)out_size; (void)ws_size;
    const float* x  = (const float*)d_in[0];
    const float* W1 = (const float*)d_in[1];
    const float* b1 = (const float*)d_in[2];
    const float* W2 = (const float*)d_in[3];
    const float* b2 = (const float*)d_in[4];
    const float* qp = (const float*)d_in[5];
    const float* W3 = (const float*)d_in[6];
    const float* b3 = (const float*)d_in[7];
    const float* W4 = (const float*)d_in[8];
    const float* b4 = (const float*)d_in[9];
    float* ws  = (float*)d_ws;
    float* out = (float*)d_out;

    k_prep<<<1, 64, 0, stream>>>(qp, ws);
    k_qsim<<<4096, 256, 0, stream>>>(x, W1, b1, W2, b2, ws, W3, b3, W4, b4, out);
}